// Round 1
// baseline (1230.989 us; speedup 1.0000x reference)
//
#include <hip/hip_runtime.h>

#define NPTS 131072
#define DIM 64
#define KC 1024
#define TK 128          // clusters staged in LDS per tile
#define BLK 256

// ---------------- kernel A: embedding row norms ----------------
__global__ void enorm_kernel(const float* __restrict__ emb, float* __restrict__ enorm) {
    int k = blockIdx.x * blockDim.x + threadIdx.x;
    if (k < KC) {
        const float4* e = (const float4*)(emb + (size_t)k * DIM);
        float s = 0.f;
#pragma unroll
        for (int j = 0; j < DIM / 4; ++j) {
            float4 v = e[j];
            s += v.x * v.x + v.y * v.y + v.z * v.z + v.w * v.w;
        }
        enorm[k] = s;
    }
}

// ---------------- kernel B: assign + distortion + segment-sum scatter ----------------
__global__ __launch_bounds__(BLK) void assign_kernel(
    const float* __restrict__ x, const float* __restrict__ emb,
    const float* __restrict__ enorm,
    float* __restrict__ count, float* __restrict__ weight,
    double* __restrict__ dacc)
{
    __shared__ float4 eT[TK * (DIM / 4)];   // 128 x 64 f32 = 32 KB
    __shared__ float  eN[TK];
    __shared__ float  wsum[BLK / 64];

    const int tid = threadIdx.x;
    const int pt  = blockIdx.x * BLK + tid;

    // x point -> registers (64 f32 as 16 float4)
    float4 xr[DIM / 4];
    const float4* xp = (const float4*)(x + (size_t)pt * DIM);
#pragma unroll
    for (int j = 0; j < DIM / 4; ++j) xr[j] = xp[j];

    float best  = 3.4e38f;
    int   bestk = 0;

    for (int t = 0; t < KC / TK; ++t) {
        __syncthreads();
        // cooperative stage of 128-cluster tile: 2048 float4 / 256 thr = 8 each
        const float4* ep = (const float4*)(emb + (size_t)t * TK * DIM);
#pragma unroll
        for (int j = 0; j < (TK * DIM / 4) / BLK; ++j)
            eT[j * BLK + tid] = ep[j * BLK + tid];
        if (tid < TK) eN[tid] = enorm[t * TK + tid];
        __syncthreads();

        for (int k = 0; k < TK; ++k) {
            const float4* ek = &eT[k * (DIM / 4)];
            float d0 = 0.f, d1 = 0.f, d2 = 0.f, d3 = 0.f;
#pragma unroll
            for (int j = 0; j < DIM / 4; ++j) {
                float4 e4 = ek[j];
                d0 = fmaf(xr[j].x, e4.x, d0);
                d1 = fmaf(xr[j].y, e4.y, d1);
                d2 = fmaf(xr[j].z, e4.z, d2);
                d3 = fmaf(xr[j].w, e4.w, d3);
            }
            float s = fmaf(-2.f, (d0 + d1) + (d2 + d3), eN[k]);
            if (s < best) { best = s; bestk = t * TK + k; }
        }
    }

    // ||x||^2
    float xn = 0.f;
#pragma unroll
    for (int j = 0; j < DIM / 4; ++j)
        xn += xr[j].x * xr[j].x + xr[j].y * xr[j].y + xr[j].z * xr[j].z + xr[j].w * xr[j].w;
    float dloc = xn + best;   // = min_k ||x - e_k||^2

    // block-reduce distortion, one double atomic per block
#pragma unroll
    for (int off = 32; off > 0; off >>= 1) dloc += __shfl_down(dloc, off, 64);
    if ((tid & 63) == 0) wsum[tid >> 6] = dloc;
    __syncthreads();
    if (tid == 0) {
        float b = wsum[0] + wsum[1] + wsum[2] + wsum[3];
        atomicAdd(dacc, (double)b);
    }

    // segment-sum scatter (native fp32 HW atomics)
    unsafeAtomicAdd(&count[bestk], 1.0f);
    float* w = weight + (size_t)bestk * DIM;
#pragma unroll
    for (int j = 0; j < DIM / 4; ++j) {
        unsafeAtomicAdd(&w[4 * j + 0], xr[j].x);
        unsafeAtomicAdd(&w[4 * j + 1], xr[j].y);
        unsafeAtomicAdd(&w[4 * j + 2], xr[j].z);
        unsafeAtomicAdd(&w[4 * j + 3], xr[j].w);
    }
}

// ---------------- kernel C: finalize -> d_out ----------------
__global__ void finalize_kernel(const float* __restrict__ count,
                                const float* __restrict__ weight,
                                const double* __restrict__ dacc,
                                float* __restrict__ out)
{
    int idx = blockIdx.x * BLK + threadIdx.x;
    const float denomf = (float)(131072.0 + (double)KC * 1.0e-5);  // n + K*eps, fp32-rounded
    if (idx < KC * DIM) {
        int k = idx >> 6;
        float cn = (count[k] + 1e-5f) / denomf * 131072.0f;
        out[1 + idx] = weight[idx] / cn;
    } else if (idx < KC * DIM + KC) {
        int k = idx - KC * DIM;
        float cn = (count[k] + 1e-5f) / denomf * 131072.0f;
        out[1 + KC * DIM + k] = cn;
    } else if (idx == KC * DIM + KC) {
        out[0] = (float)(*dacc * (1.0 / ((double)NPTS * (double)DIM)));
    }
}

extern "C" void kernel_launch(void* const* d_in, const int* in_sizes, int n_in,
                              void* d_out, int out_size, void* d_ws, size_t ws_size,
                              hipStream_t stream)
{
    // inputs: [0]=it (int scalar, unused), [1]=x_flat f32 [N,D], [2]=embedding f32 [K,D]
    const float* x   = (const float*)d_in[1];
    const float* emb = (const float*)d_in[2];
    float* out = (float*)d_out;

    // ws layout: enorm[K] | count[K] | weight[K*D] | dacc (double, 8B-aligned)
    float*  enorm  = (float*)d_ws;
    float*  count  = enorm + KC;
    float*  weight = count + KC;
    size_t  daccOff = (size_t)(2 * KC + KC * DIM) * sizeof(float);  // 270336, 8B aligned
    double* dacc   = (double*)((char*)d_ws + daccOff);

    hipMemsetAsync(d_ws, 0, daccOff + sizeof(double), stream);

    enorm_kernel<<<(KC + BLK - 1) / BLK, BLK, 0, stream>>>(emb, enorm);
    assign_kernel<<<NPTS / BLK, BLK, 0, stream>>>(x, emb, enorm, count, weight, dacc);

    int fin_elems = KC * DIM + KC + 1;
    finalize_kernel<<<(fin_elems + BLK - 1) / BLK, BLK, 0, stream>>>(count, weight, dacc, out);
}